// Round 3
// baseline (1554.280 us; speedup 1.0000x reference)
//
#include <hip/hip_runtime.h>

typedef unsigned short u16;
typedef __attribute__((ext_vector_type(8))) short short8;
typedef __attribute__((ext_vector_type(4))) float f32x4;

__device__ __forceinline__ float b2f(u16 u) {
  unsigned x = ((unsigned)u) << 16;
  return __uint_as_float(x);
}
__device__ __forceinline__ u16 f2b(float f) {
  unsigned x = __float_as_uint(f);
  x += 0x7fffu + ((x >> 16) & 1u);
  return (u16)(x >> 16);
}
__device__ __forceinline__ unsigned fkey(float f) {
  unsigned b = __float_as_uint(f);
  return (b & 0x80000000u) ? ~b : (b | 0x80000000u);
}
__device__ __forceinline__ float unfkey(unsigned u) {
  unsigned b = (u & 0x80000000u) ? (u ^ 0x80000000u) : ~u;
  return __uint_as_float(b);
}

// ---------------------------------------------------------------------------
// dtype detector (insurance): flag=1 means inputs are f32 (expected), 0 bf16
// ---------------------------------------------------------------------------
__global__ void detect_dtype(const u16* __restrict__ X, int* __restrict__ flag) {
  __shared__ int cnt;
  if (threadIdx.x == 0) cnt = 0;
  __syncthreads();
  int sane = 0;
#pragma unroll
  for (int j = 0; j < 16; ++j) {
    u16 u = X[(threadIdx.x * 16 + j) * 2];
    int e = (u >> 7) & 0xff;
    if (u == 0 || (e >= 112 && e <= 142)) sane++;
  }
  atomicAdd(&cnt, sane);
  __syncthreads();
  if (threadIdx.x == 0) *flag = (cnt < 3072) ? 1 : 0;
}

// split input to hi/lo bf16 (lo = residual); handles f32 or bf16 input
__global__ __launch_bounds__(256) void split_input(
    const void* __restrict__ in, u16* __restrict__ hi, u16* __restrict__ lo,
    int n, const int* __restrict__ flag) {
  int f = *flag;
  int stride = gridDim.x * 256;
  for (int i = blockIdx.x * 256 + threadIdx.x; i < n; i += stride) {
    float x = f ? ((const float*)in)[i] : b2f(((const u16*)in)[i]);
    u16 h = f2b(x);
    hi[i] = h;
    lo[i] = f2b(x - b2f(h));
  }
}

// split f32 buffer to hi/lo bf16
__global__ __launch_bounds__(256) void split_f32(
    const float* __restrict__ in, u16* __restrict__ hi, u16* __restrict__ lo,
    int n) {
  int stride = gridDim.x * 256;
  for (int i = blockIdx.x * 256 + threadIdx.x; i < n; i += stride) {
    float x = in[i];
    u16 h = f2b(x);
    hi[i] = h;
    lo[i] = f2b(x - b2f(h));
  }
}

// plain bf16 canonicalize (for proj_w)
__global__ __launch_bounds__(256) void conv_bf16(const void* __restrict__ in,
                                                 u16* __restrict__ out, int n,
                                                 const int* __restrict__ flag) {
  int f = *flag;
  int stride = gridDim.x * 256;
  for (int i = blockIdx.x * 256 + threadIdx.x; i < n; i += stride)
    out[i] = f ? f2b(((const float*)in)[i]) : ((const u16*)in)[i];
}

// canonicalize to f32 (theta, proj_b)
__global__ __launch_bounds__(256) void conv_f32(const void* __restrict__ in,
                                                float* __restrict__ out, int n,
                                                const int* __restrict__ flag) {
  int f = *flag;
  int stride = gridDim.x * 256;
  for (int i = blockIdx.x * 256 + threadIdx.x; i < n; i += stride)
    out[i] = f ? ((const float*)in)[i] : b2f(((const u16*)in)[i]);
}

// ---------------------------------------------------------------------------
// NT GEMM: C[M,Nc] (f32) = alpha * A[M,K] * B[Nc,K]^T (bf16 operands, K-fast)
// 64x64 tile, 4 waves, mfma_f32_16x16x32_bf16.
// ---------------------------------------------------------------------------
template <bool ACCUM, bool BIAS, bool SCALEPTR>
__global__ __launch_bounds__(256) void gemm_nt(
    const u16* __restrict__ A, const u16* __restrict__ B, float* __restrict__ C,
    const float* __restrict__ bias, const float* __restrict__ scptr, float alpha,
    int M, int Nc, int Kd, long batchA, long batchB, long batchC) {
  const u16* Ab = A + (size_t)blockIdx.z * batchA;
  const u16* Bb = B + (size_t)blockIdx.z * batchB;
  float* Cb = C + (size_t)blockIdx.z * batchC;
  int bn = blockIdx.x, bm = blockIdx.y;
  int tid = threadIdx.x;
  int wid = tid >> 6, lane = tid & 63;
  __shared__ u16 As[64 * 40];
  __shared__ u16 Bs[64 * 40];
  f32x4 acc00 = {}, acc01 = {}, acc10 = {}, acc11 = {};
  int lr = tid >> 2;
  int lc = (tid & 3) << 3;
  const u16* Ag = Ab + (size_t)(bm * 64 + lr) * Kd + lc;
  const u16* Bg = Bb + (size_t)(bn * 64 + lr) * Kd + lc;
  int wm = (wid & 1) * 32, wn = (wid >> 1) * 32;
  int fr = lane & 15;
  int fc = (lane >> 4) << 3;
  for (int k0 = 0; k0 < Kd; k0 += 32) {
    uint4 av = *(const uint4*)(Ag + k0);
    uint4 bv = *(const uint4*)(Bg + k0);
    __syncthreads();
    *(uint4*)(As + lr * 40 + lc) = av;
    *(uint4*)(Bs + lr * 40 + lc) = bv;
    __syncthreads();
    short8 a0 = *(const short8*)(As + (wm + fr) * 40 + fc);
    short8 a1 = *(const short8*)(As + (wm + 16 + fr) * 40 + fc);
    short8 b0 = *(const short8*)(Bs + (wn + fr) * 40 + fc);
    short8 b1 = *(const short8*)(Bs + (wn + 16 + fr) * 40 + fc);
    acc00 = __builtin_amdgcn_mfma_f32_16x16x32_bf16(a0, b0, acc00, 0, 0, 0);
    acc01 = __builtin_amdgcn_mfma_f32_16x16x32_bf16(a0, b1, acc01, 0, 0, 0);
    acc10 = __builtin_amdgcn_mfma_f32_16x16x32_bf16(a1, b0, acc10, 0, 0, 0);
    acc11 = __builtin_amdgcn_mfma_f32_16x16x32_bf16(a1, b1, acc11, 0, 0, 0);
  }
  float sc = alpha;
  if constexpr (SCALEPTR) sc *= *scptr;
  int crow = (lane >> 4) << 2;
  int ccol = lane & 15;
  f32x4 accs[2][2] = {{acc00, acc01}, {acc10, acc11}};
#pragma unroll
  for (int i = 0; i < 2; ++i)
#pragma unroll
    for (int j = 0; j < 2; ++j) {
      int r0 = bm * 64 + wm + 16 * i + crow;
      int c0 = bn * 64 + wn + 16 * j + ccol;
#pragma unroll
      for (int rg = 0; rg < 4; ++rg) {
        size_t off = (size_t)(r0 + rg) * Nc + c0;
        float v = accs[i][j][rg] * sc;
        if constexpr (BIAS) v += bias[c0];
        if constexpr (ACCUM)
          Cb[off] += v;
        else
          Cb[off] = v;
      }
    }
}

// ---------------------------------------------------------------------------
// bf16 transpose: out[c][r] = in[r][c]
// ---------------------------------------------------------------------------
__global__ __launch_bounds__(256) void transpose_bf16(
    const u16* __restrict__ in, u16* __restrict__ out, int rows, int cols) {
  __shared__ u16 t[32][33];
  const u16* ib = in + (size_t)blockIdx.z * rows * cols;
  u16* ob = out + (size_t)blockIdx.z * rows * cols;
  int r0 = blockIdx.x * 32, c0 = blockIdx.y * 32;
  int tx = threadIdx.x & 31, ty = threadIdx.x >> 5;
#pragma unroll
  for (int i = 0; i < 32; i += 8)
    t[ty + i][tx] = ib[(size_t)(r0 + ty + i) * cols + c0 + tx];
  __syncthreads();
#pragma unroll
  for (int i = 0; i < 32; i += 8)
    ob[(size_t)(c0 + ty + i) * rows + r0 + tx] = t[tx][ty + i];
}

// ---------------------------------------------------------------------------
// scalars: w = softmax(alpha) -> scal[0..3], rho = sigmoid(rho_raw) -> scal[4]
// ---------------------------------------------------------------------------
__global__ void prep_scalars(const void* __restrict__ alpha,
                             const void* __restrict__ rho_raw,
                             float* __restrict__ scal,
                             const int* __restrict__ flag) {
  if (threadIdx.x == 0) {
    int f = *flag;
    float a[4], e[4], m = -1e30f, s = 0.f;
    for (int i = 0; i < 4; ++i) {
      a[i] = f ? ((const float*)alpha)[i] : b2f(((const u16*)alpha)[i]);
      m = fmaxf(m, a[i]);
    }
    for (int i = 0; i < 4; ++i) { e[i] = expf(a[i] - m); s += e[i]; }
    for (int i = 0; i < 4; ++i) scal[i] = e[i] / s;
    float rr = f ? ((const float*)rho_raw)[0] : b2f(((const u16*)rho_raw)[0]);
    scal[4] = 1.f / (1.f + expf(-rr));
  }
}

// ---------------------------------------------------------------------------
// per-row softmax stats + top-16 (jax top_k tiebreak: lowest index on ties)
// one wave per row
// ---------------------------------------------------------------------------
__global__ __launch_bounds__(256) void rowstat_topk(
    const float* __restrict__ A, float* __restrict__ topv,
    int* __restrict__ topi, float* __restrict__ rowM,
    float* __restrict__ rowSinv, int khead) {
  int wid = threadIdx.x >> 6, lane = threadIdx.x & 63;
  int row = blockIdx.x * 4 + wid;
  const float* arow = A + ((size_t)row << 12);
  float tv[16];
  int ti[16];
#pragma unroll
  for (int j = 0; j < 16; ++j) { tv[j] = -INFINITY; ti[j] = 0; }
  float m = -INFINITY, s = 0.f;
  for (int t = 0; t < 64; ++t) {
    int c = lane + (t << 6);
    float v = arow[c];
    if (v > m) { s = s * expf(m - v) + 1.f; m = v; }
    else s += expf(v - m);
    if (v > tv[15]) {
      tv[15] = v; ti[15] = c;
#pragma unroll
      for (int j = 15; j >= 1; --j) {
        if (tv[j] > tv[j - 1]) {
          float tf = tv[j]; tv[j] = tv[j - 1]; tv[j - 1] = tf;
          int tq = ti[j]; ti[j] = ti[j - 1]; ti[j - 1] = tq;
        }
      }
    }
  }
#pragma unroll
  for (int off = 32; off; off >>= 1) {
    float m2 = __shfl_xor(m, off);
    float s2 = __shfl_xor(s, off);
    float M = fmaxf(m, m2);
    s = s * expf(m - M) + s2 * expf(m2 - M);
    m = M;
  }
  float invS = 1.f / s;
  float myv = 0.f; int myi = 0; float sum16 = 0.f;
  for (int r = 0; r < 16; ++r) {
    unsigned long long key =
        ((unsigned long long)fkey(tv[0]) << 32) | (unsigned)(~(unsigned)ti[0]);
    unsigned long long k2 = key;
#pragma unroll
    for (int off = 32; off; off >>= 1) {
      unsigned long long o = __shfl_xor(k2, off);
      if (o > k2) k2 = o;
    }
    float wv = unfkey((unsigned)(k2 >> 32));
    int wi = (int)(~(unsigned)(k2 & 0xffffffffu));
    if (key == k2) {
#pragma unroll
      for (int j = 0; j < 15; ++j) { tv[j] = tv[j + 1]; ti[j] = ti[j + 1]; }
      tv[15] = -INFINITY; ti[15] = 0;
    }
    sum16 += expf(wv - m);
    if (r == lane) { myv = wv; myi = wi; }
  }
  if (lane < 16) {
    float h = expf(myv - m) * invS;
    float dn = sum16 * invS + 1e-9f;
    size_t o = (((size_t)khead << 12) + row) * 16 + lane;
    topv[o] = h / dn;
    topi[o] = myi;
  }
  if (lane == 0) { rowM[row] = m; rowSinv[row] = invS; }
}

// P[n,m] = bf16( exp(A-M)*invS )
__global__ __launch_bounds__(256) void softmax_p(
    const float* __restrict__ A, const float* __restrict__ rowM,
    const float* __restrict__ rowSinv, u16* __restrict__ P) {
  int row = blockIdx.y;
  int c = (blockIdx.x * 256 + threadIdx.x) * 4;
  size_t o = ((size_t)row << 12) + c;
  float m = rowM[row], si = rowSinv[row];
  float4 v = *(const float4*)(A + o);
  ushort4 b;
  b.x = f2b(expf(v.x - m) * si);
  b.y = f2b(expf(v.y - m) * si);
  b.z = f2b(expf(v.z - m) * si);
  b.w = f2b(expf(v.w - m) * si);
  *(ushort4*)(P + o) = b;
}

// scatter S += b_e b_e^T / De, Dv += b_e  (one wave per hyperedge)
__global__ __launch_bounds__(256) void edge_scatter(
    const float* __restrict__ topv, const int* __restrict__ topi,
    float* __restrict__ S, float* __restrict__ Dv) {
  int wid = threadIdx.x >> 6, lane = threadIdx.x & 63;
  int e = blockIdx.x * 4 + wid;
  float v = 0.f; int ix = 0;
  if (lane < 16) {
    v = topv[((size_t)e << 4) + lane];
    ix = topi[((size_t)e << 4) + lane];
  }
  float de = v;
#pragma unroll
  for (int off = 8; off; off >>= 1) de += __shfl_xor(de, off);
  de = __shfl(de, 0);
  float inv = 1.f / (de + 1e-9f);
  if (lane < 16) atomicAdd(&Dv[ix], v);
#pragma unroll
  for (int p = 0; p < 4; ++p) {
    int j1 = (lane >> 4) + (p << 2);
    int j2 = lane & 15;
    float v1 = __shfl(v, j1);
    float v2 = __shfl(v, j2);
    int i1 = __shfl(ix, j1);
    int i2 = __shfl(ix, j2);
    atomicAdd(&S[((size_t)i1 << 12) + i2], v1 * v2 * inv);
  }
}

__global__ void dv_isqrt(const float* __restrict__ Dv, float* __restrict__ Dvis) {
  int i = blockIdx.x * 256 + threadIdx.x;
  Dvis[i] = sqrtf(1.0f / (Dv[i] + 1e-9f));
}

// S_norm in place (f32) + bf16 copy
__global__ __launch_bounds__(256) void sn_scale(
    float* __restrict__ S, const float* __restrict__ Dvis, u16* __restrict__ Sbf) {
  int row = blockIdx.y;
  int c = (blockIdx.x * 256 + threadIdx.x) * 4;
  size_t o = ((size_t)row << 12) + c;
  float dr = Dvis[row];
  float4 s = *(float4*)(S + o);
  s.x *= dr * Dvis[c];
  s.y *= dr * Dvis[c + 1];
  s.z *= dr * Dvis[c + 2];
  s.w *= dr * Dvis[c + 3];
  *(float4*)(S + o) = s;
  ushort4 b;
  b.x = f2b(s.x); b.y = f2b(s.y); b.z = f2b(s.z); b.w = f2b(s.w);
  *(ushort4*)(Sbf + o) = b;
}

// v0: bit-exact jax.random.normal(key(1), (4096,1), f32)
__global__ __launch_bounds__(256) void init_v0(float* __restrict__ v) {
  int tid = blockIdx.x * 256 + threadIdx.x;
  unsigned j = (unsigned)(tid & 2047);
  unsigned x0 = j, x1 = j + 2048u;
  const unsigned ks0 = 0u, ks1 = 1u, ks2 = 0x1BD11BDAu;  // 0^1^0x1BD11BDB
  x0 += ks0; x1 += ks1;
#define TF_R(r)                                  \
  {                                              \
    x0 += x1;                                    \
    x1 = (x1 << (r)) | (x1 >> (32 - (r)));       \
    x1 ^= x0;                                    \
  }
  TF_R(13) TF_R(15) TF_R(26) TF_R(6)  x0 += ks1; x1 += ks2 + 1u;
  TF_R(17) TF_R(29) TF_R(16) TF_R(24) x0 += ks2; x1 += ks0 + 2u;
  TF_R(13) TF_R(15) TF_R(26) TF_R(6)  x0 += ks0; x1 += ks1 + 3u;
  TF_R(17) TF_R(29) TF_R(16) TF_R(24) x0 += ks1; x1 += ks2 + 4u;
  TF_R(13) TF_R(15) TF_R(26) TF_R(6)  x0 += ks2; x1 += ks0 + 5u;
#undef TF_R
  unsigned bits = (tid < 2048) ? x0 : x1;
  float u01 = __uint_as_float((bits >> 9) | 0x3f800000u) - 1.0f;
  const float lo = -0.99999994f;
  float u = fmaxf(lo, u01 * 2.0f + lo);
  float w = -log1pf(-u * u);
  float p;
  if (w < 5.0f) {
    float t = w - 2.5f;
    p = 2.81022636e-08f;
    p = 3.43273939e-07f + p * t;
    p = -3.5233877e-06f + p * t;
    p = -4.39150654e-06f + p * t;
    p = 0.00021858087f + p * t;
    p = -0.00125372503f + p * t;
    p = -0.00417768164f + p * t;
    p = 0.246640727f + p * t;
    p = 1.50140941f + p * t;
  } else {
    float t = sqrtf(w) - 3.0f;
    p = -0.000200214257f;
    p = 0.000100950558f + p * t;
    p = 0.00134934322f + p * t;
    p = -0.00367342844f + p * t;
    p = 0.00573950773f + p * t;
    p = -0.0076224613f + p * t;
    p = 0.00943887047f + p * t;
    p = 1.00167406f + p * t;
    p = 2.83297682f + p * t;
  }
  v[tid] = 1.41421354f * (p * u);
}

// u = v - S_norm @ v  (one wave per row, v staged in LDS)
__global__ __launch_bounds__(256) void lap_matvec(
    const float* __restrict__ S, const float* __restrict__ vin,
    float* __restrict__ vout) {
  __shared__ float vv[4096];
  int tid = threadIdx.x;
  for (int i = tid; i < 4096; i += 256) vv[i] = vin[i];
  __syncthreads();
  int wid = tid >> 6, lane = tid & 63;
  int row = blockIdx.x * 4 + wid;
  const float* sr = S + ((size_t)row << 12);
  float acc = 0.f;
#pragma unroll 8
  for (int t = 0; t < 64; ++t) {
    int c = lane + (t << 6);
    acc += sr[c] * vv[c];
  }
#pragma unroll
  for (int off = 32; off; off >>= 1) acc += __shfl_xor(acc, off);
  if (lane == 0) vout[row] = vv[row] - acc;
}

// lam = clip((w5.w6)/(w5.w5), 1e-3) -> scal[5]
__global__ __launch_bounds__(256) void pi_dots(const float* __restrict__ w5,
                                               const float* __restrict__ w6,
                                               float* __restrict__ scal) {
  __shared__ float r1[256], r2[256];
  int tid = threadIdx.x;
  float a = 0.f, b = 0.f;
  for (int i = tid; i < 4096; i += 256) {
    float x = w5[i];
    a += x * x;
    b += x * w6[i];
  }
  r1[tid] = a; r2[tid] = b;
  __syncthreads();
  for (int off = 128; off; off >>= 1) {
    if (tid < off) { r1[tid] += r1[tid + off]; r2[tid] += r2[tid + off]; }
    __syncthreads();
  }
  if (tid == 0) scal[5] = fmaxf(r2[0] / r1[0], 1e-3f);
}

// T1 = (c1-1)X - c1*SnX (f32 X source); also write T1^T bf16
__global__ __launch_bounds__(256) void t1_kernel(
    const float* __restrict__ SnX, const u16* __restrict__ Xhi,
    const u16* __restrict__ Xlo, const float* __restrict__ scal,
    float* __restrict__ T1, u16* __restrict__ T1T) {
  __shared__ u16 t[32][33];
  float c1 = 2.0f / scal[5];
  int r0 = blockIdx.x * 32, c0 = blockIdx.y * 32;
  int tx = threadIdx.x & 31, ty = threadIdx.x >> 5;
#pragma unroll
  for (int i = 0; i < 32; i += 8) {
    size_t off = (size_t)(r0 + ty + i) * 256 + c0 + tx;
    float x = b2f(Xhi[off]) + b2f(Xlo[off]);
    float v = (c1 - 1.0f) * x - c1 * SnX[off];
    T1[off] = v;
    t[ty + i][tx] = f2b(v);
  }
  __syncthreads();
#pragma unroll
  for (int i = 0; i < 32; i += 8)
    T1T[(size_t)(c0 + ty + i) * 4096 + r0 + tx] = t[tx][ty + i];
}

// T2, cheb combine, elu, mix -> Zmix bf16 for final projection
__global__ __launch_bounds__(256) void combine_kernel(
    const u16* __restrict__ Xhi, const u16* __restrict__ Xlo,
    const float* __restrict__ T1, const float* __restrict__ SnT1,
    const float* __restrict__ Zk, const float* __restrict__ thetaf,
    const float* __restrict__ scal, u16* __restrict__ Zmixb) {
  int idx = blockIdx.x * 256 + threadIdx.x;
  int d = idx & 255;
  float c1 = 2.0f / scal[5];
  float rho = scal[4];
  float x = b2f(Xhi[idx]) + b2f(Xlo[idx]);
  float t1 = T1[idx];
  float t2 = 2.0f * ((c1 - 1.0f) * t1 - c1 * SnT1[idx]) - x;
  float o = x * thetaf[d] + t1 * thetaf[256 + d] + t2 * thetaf[512 + d];
  float zs = o > 0.0f ? o : expm1f(o);
  float zm = rho * zs + (1.0f - rho) * Zk[idx];
  Zmixb[idx] = f2b(zm);
}

// ---------------------------------------------------------------------------
extern "C" void kernel_launch(void* const* d_in, const int* in_sizes, int n_in,
                              void* d_out, int out_size, void* d_ws,
                              size_t ws_size, hipStream_t stream) {
  (void)in_sizes; (void)n_in; (void)out_size;
  const void* Xin = d_in[0];
  const void* Lin = d_in[1];
  const void* alpha = d_in[2];
  const void* theta = d_in[3];
  const void* rho_raw = d_in[4];
  const void* Wpin = d_in[5];
  const void* bpin = d_in[6];
  float* out = (float*)d_out;  // reference output dtype = float32

  char* base = (char*)d_ws;
  size_t off = 0;
  auto alloc = [&](size_t bytes) -> char* {
    char* p = base + off;
    off += (bytes + 255) & ~(size_t)255;
    return p;
  };
  float* Abuf = (float*)alloc((size_t)4096 * 4096 * 4);   // A_k, then S/S_norm
  u16* Pbuf = (u16*)alloc((size_t)4096 * 4096 * 2);       // Yf alias; P_k; Sn bf16
  u16* Yhi = (u16*)alloc((size_t)4 * 4096 * 256 * 2);
  u16* Ylo = (u16*)alloc((size_t)4 * 4096 * 256 * 2);
  u16* Xhi = (u16*)alloc((size_t)4096 * 256 * 2);
  u16* Xlo = (u16*)alloc((size_t)4096 * 256 * 2);
  u16* XT = (u16*)alloc((size_t)256 * 4096 * 2);
  u16* Lhi = (u16*)alloc((size_t)4 * 256 * 256 * 2);
  u16* Llo = (u16*)alloc((size_t)4 * 256 * 256 * 2);
  u16* LThi = (u16*)alloc((size_t)4 * 256 * 256 * 2);
  u16* LTlo = (u16*)alloc((size_t)4 * 256 * 256 * 2);
  u16* Wbf = (u16*)alloc((size_t)256 * 256 * 2);
  float* Zk = (float*)alloc((size_t)4096 * 256 * 4);
  float* SnX = (float*)alloc((size_t)4096 * 256 * 4);     // also SnT1
  float* T1 = (float*)alloc((size_t)4096 * 256 * 4);
  u16* T1T = (u16*)alloc((size_t)256 * 4096 * 2);
  u16* Zmixb = (u16*)alloc((size_t)4096 * 256 * 2);
  float* topv = (float*)alloc((size_t)4 * 4096 * 16 * 4);
  int* topi = (int*)alloc((size_t)4 * 4096 * 16 * 4);
  float* rowM = (float*)alloc(4096 * 4);
  float* rowSinv = (float*)alloc(4096 * 4);
  float* Dv = (float*)alloc(4096 * 4);
  float* Dvis = (float*)alloc(4096 * 4);
  float* wA = (float*)alloc(4096 * 4);
  float* wB = (float*)alloc(4096 * 4);
  float* thetaf = (float*)alloc(768 * 4);
  float* biasf = (float*)alloc(256 * 4);
  float* scal = (float*)alloc(256);
  int* flag = (int*)alloc(256);
  if (off > ws_size) return;
  float* Yf = (float*)Pbuf;  // 16 MB alias inside 32 MB Pbuf; dead before P use

  detect_dtype<<<1, 256, 0, stream>>>((const u16*)Xin, flag);
  split_input<<<1024, 256, 0, stream>>>(Xin, Xhi, Xlo, 4096 * 256, flag);
  split_input<<<256, 256, 0, stream>>>(Lin, Lhi, Llo, 4 * 256 * 256, flag);
  conv_bf16<<<64, 256, 0, stream>>>(Wpin, Wbf, 256 * 256, flag);
  conv_f32<<<1, 256, 0, stream>>>(theta, thetaf, 768, flag);
  conv_f32<<<1, 256, 0, stream>>>(bpin, biasf, 256, flag);
  prep_scalars<<<1, 64, 0, stream>>>(alpha, rho_raw, scal, flag);
  transpose_bf16<<<dim3(128, 8, 1), 256, 0, stream>>>(Xhi, XT, 4096, 256);
  transpose_bf16<<<dim3(8, 8, 4), 256, 0, stream>>>(Lhi, LThi, 256, 256);
  transpose_bf16<<<dim3(8, 8, 4), 256, 0, stream>>>(Llo, LTlo, 256, 256);
  // Yf = X @ L_k in split precision (hi*hi + hi*lo + lo*hi), batched z=4
  gemm_nt<false, false, false><<<dim3(4, 64, 4), 256, 0, stream>>>(
      Xhi, LThi, Yf, nullptr, nullptr, 1.0f, 4096, 256, 256,
      0L, 256L * 256L, 4096L * 256L);
  gemm_nt<true, false, false><<<dim3(4, 64, 4), 256, 0, stream>>>(
      Xhi, LTlo, Yf, nullptr, nullptr, 1.0f, 4096, 256, 256,
      0L, 256L * 256L, 4096L * 256L);
  gemm_nt<true, false, false><<<dim3(4, 64, 4), 256, 0, stream>>>(
      Xlo, LThi, Yf, nullptr, nullptr, 1.0f, 4096, 256, 256,
      0L, 256L * 256L, 4096L * 256L);
  split_f32<<<2048, 256, 0, stream>>>(Yf, Yhi, Ylo, 4 * 4096 * 256);
  hipMemsetAsync(Zk, 0, (size_t)4096 * 256 * 4, stream);
  for (int k = 0; k < 4; ++k) {
    const u16* Yhk = Yhi + (size_t)k * 4096 * 256;
    const u16* Ylk = Ylo + (size_t)k * 4096 * 256;
    // A = Y_k @ X^T / 16 in split precision
    gemm_nt<false, false, false><<<dim3(64, 64, 1), 256, 0, stream>>>(
        Yhk, Xhi, Abuf, nullptr, nullptr, 0.0625f, 4096, 4096, 256, 0L, 0L, 0L);
    gemm_nt<true, false, false><<<dim3(64, 64, 1), 256, 0, stream>>>(
        Yhk, Xlo, Abuf, nullptr, nullptr, 0.0625f, 4096, 4096, 256, 0L, 0L, 0L);
    gemm_nt<true, false, false><<<dim3(64, 64, 1), 256, 0, stream>>>(
        Ylk, Xhi, Abuf, nullptr, nullptr, 0.0625f, 4096, 4096, 256, 0L, 0L, 0L);
    rowstat_topk<<<1024, 256, 0, stream>>>(Abuf, topv, topi, rowM, rowSinv, k);
    softmax_p<<<dim3(4, 4096), 256, 0, stream>>>(Abuf, rowM, rowSinv, Pbuf);
    // Zk += w_k * P @ X
    gemm_nt<true, false, true><<<dim3(4, 64, 1), 256, 0, stream>>>(
        Pbuf, XT, Zk, nullptr, scal + k, 1.0f, 4096, 256, 4096, 0L, 0L, 0L);
  }
  hipMemsetAsync(Abuf, 0, (size_t)4096 * 4096 * 4, stream);
  hipMemsetAsync(Dv, 0, 4096 * 4, stream);
  edge_scatter<<<4096, 256, 0, stream>>>(topv, topi, Abuf, Dv);
  dv_isqrt<<<16, 256, 0, stream>>>(Dv, Dvis);
  sn_scale<<<dim3(4, 4096), 256, 0, stream>>>(Abuf, Dvis, Pbuf);
  init_v0<<<16, 256, 0, stream>>>(wA);
  for (int it = 0; it < 6; ++it)
    lap_matvec<<<1024, 256, 0, stream>>>(Abuf, (it & 1) ? wB : wA,
                                         (it & 1) ? wA : wB);
  pi_dots<<<1, 256, 0, stream>>>(wB, wA, scal);
  // SnX = S_norm @ X
  gemm_nt<false, false, false><<<dim3(4, 64, 1), 256, 0, stream>>>(
      Pbuf, XT, SnX, nullptr, nullptr, 1.0f, 4096, 256, 4096, 0L, 0L, 0L);
  t1_kernel<<<dim3(128, 8), 256, 0, stream>>>(SnX, Xhi, Xlo, scal, T1, T1T);
  // SnT1 = S_norm @ T1 (into SnX buffer)
  gemm_nt<false, false, false><<<dim3(4, 64, 1), 256, 0, stream>>>(
      Pbuf, T1T, SnX, nullptr, nullptr, 1.0f, 4096, 256, 4096, 0L, 0L, 0L);
  combine_kernel<<<4096, 256, 0, stream>>>(Xhi, Xlo, T1, SnX, Zk, thetaf, scal,
                                           Zmixb);
  // out = Zmix @ proj_w^T + proj_b  (f32 out)
  gemm_nt<false, true, false><<<dim3(4, 64, 1), 256, 0, stream>>>(
      Zmixb, Wbf, out, biasf, nullptr, 1.0f, 4096, 256, 256, 0L, 0L, 0L);
}

// Round 4
// 1142.022 us; speedup vs baseline: 1.3610x; 1.3610x over previous
//
#include <hip/hip_runtime.h>

typedef unsigned short u16;
typedef __attribute__((ext_vector_type(8))) short short8;
typedef __attribute__((ext_vector_type(4))) float f32x4;

__device__ __forceinline__ float b2f(u16 u) {
  unsigned x = ((unsigned)u) << 16;
  return __uint_as_float(x);
}
__device__ __forceinline__ u16 f2b(float f) {
  unsigned x = __float_as_uint(f);
  x += 0x7fffu + ((x >> 16) & 1u);
  return (u16)(x >> 16);
}
__device__ __forceinline__ unsigned fkey(float f) {
  unsigned b = __float_as_uint(f);
  return (b & 0x80000000u) ? ~b : (b | 0x80000000u);
}
__device__ __forceinline__ float unfkey(unsigned u) {
  unsigned b = (u & 0x80000000u) ? (u ^ 0x80000000u) : ~u;
  return __uint_as_float(b);
}

// dtype detector (insurance): flag=1 means inputs are f32 (expected)
__global__ void detect_dtype(const u16* __restrict__ X, int* __restrict__ flag) {
  __shared__ int cnt;
  if (threadIdx.x == 0) cnt = 0;
  __syncthreads();
  int sane = 0;
#pragma unroll
  for (int j = 0; j < 16; ++j) {
    u16 u = X[(threadIdx.x * 16 + j) * 2];
    int e = (u >> 7) & 0xff;
    if (u == 0 || (e >= 112 && e <= 142)) sane++;
  }
  atomicAdd(&cnt, sane);
  __syncthreads();
  if (threadIdx.x == 0) *flag = (cnt < 3072) ? 1 : 0;
}

// split input to hi/lo bf16 + optional f32 copy
__global__ __launch_bounds__(256) void split_input3(
    const void* __restrict__ in, u16* __restrict__ hi, u16* __restrict__ lo,
    float* __restrict__ f32out, int n, const int* __restrict__ flag) {
  int f = *flag;
  int stride = gridDim.x * 256;
  for (int i = blockIdx.x * 256 + threadIdx.x; i < n; i += stride) {
    float x = f ? ((const float*)in)[i] : b2f(((const u16*)in)[i]);
    u16 h = f2b(x);
    hi[i] = h;
    lo[i] = f2b(x - b2f(h));
    if (f32out) f32out[i] = x;
  }
}

// split f32 buffer to hi/lo bf16
__global__ __launch_bounds__(256) void split_f32(
    const float* __restrict__ in, u16* __restrict__ hi, u16* __restrict__ lo,
    int n) {
  int stride = gridDim.x * 256;
  for (int i = blockIdx.x * 256 + threadIdx.x; i < n; i += stride) {
    float x = in[i];
    u16 h = f2b(x);
    hi[i] = h;
    lo[i] = f2b(x - b2f(h));
  }
}

// canonicalize to f32 (theta, proj_b)
__global__ __launch_bounds__(256) void conv_f32(const void* __restrict__ in,
                                                float* __restrict__ out, int n,
                                                const int* __restrict__ flag) {
  int f = *flag;
  int stride = gridDim.x * 256;
  for (int i = blockIdx.x * 256 + threadIdx.x; i < n; i += stride)
    out[i] = f ? ((const float*)in)[i] : b2f(((const u16*)in)[i]);
}

// ---------------------------------------------------------------------------
// Split-precision NT GEMM: C = alpha*(Ah*Bh^T + Ah*Bl^T + Al*Bh^T)
// 64x64 tile, 4 waves, 12 MFMA per k-step. Single C write (no RMW).
// ---------------------------------------------------------------------------
template <bool BIAS>
__global__ __launch_bounds__(256) void gemm3_nt(
    const u16* __restrict__ Ah, const u16* __restrict__ Al,
    const u16* __restrict__ Bh, const u16* __restrict__ Bl,
    float* __restrict__ C, const float* __restrict__ bias, float alpha,
    int M, int Nc, int Kd, long batchA, long batchB, long batchC) {
  const u16* Abh = Ah + (size_t)blockIdx.z * batchA;
  const u16* Abl = Al + (size_t)blockIdx.z * batchA;
  const u16* Bbh = Bh + (size_t)blockIdx.z * batchB;
  const u16* Bbl = Bl + (size_t)blockIdx.z * batchB;
  float* Cb = C + (size_t)blockIdx.z * batchC;
  int bn = blockIdx.x, bm = blockIdx.y;
  int tid = threadIdx.x;
  int wid = tid >> 6, lane = tid & 63;
  __shared__ u16 Ash[64 * 40], Asl[64 * 40], Bsh[64 * 40], Bsl[64 * 40];
  f32x4 acc00 = {}, acc01 = {}, acc10 = {}, acc11 = {};
  int lr = tid >> 2;
  int lc = (tid & 3) << 3;
  size_t aoff = (size_t)(bm * 64 + lr) * Kd + lc;
  size_t boff = (size_t)(bn * 64 + lr) * Kd + lc;
  int wm = (wid & 1) * 32, wn = (wid >> 1) * 32;
  int fr = lane & 15;
  int fc = (lane >> 4) << 3;
  for (int k0 = 0; k0 < Kd; k0 += 32) {
    uint4 avh = *(const uint4*)(Abh + aoff + k0);
    uint4 avl = *(const uint4*)(Abl + aoff + k0);
    uint4 bvh = *(const uint4*)(Bbh + boff + k0);
    uint4 bvl = *(const uint4*)(Bbl + boff + k0);
    __syncthreads();
    *(uint4*)(Ash + lr * 40 + lc) = avh;
    *(uint4*)(Asl + lr * 40 + lc) = avl;
    *(uint4*)(Bsh + lr * 40 + lc) = bvh;
    *(uint4*)(Bsl + lr * 40 + lc) = bvl;
    __syncthreads();
    short8 a0h = *(const short8*)(Ash + (wm + fr) * 40 + fc);
    short8 a1h = *(const short8*)(Ash + (wm + 16 + fr) * 40 + fc);
    short8 b0h = *(const short8*)(Bsh + (wn + fr) * 40 + fc);
    short8 b1h = *(const short8*)(Bsh + (wn + 16 + fr) * 40 + fc);
    short8 a0l = *(const short8*)(Asl + (wm + fr) * 40 + fc);
    short8 a1l = *(const short8*)(Asl + (wm + 16 + fr) * 40 + fc);
    short8 b0l = *(const short8*)(Bsl + (wn + fr) * 40 + fc);
    short8 b1l = *(const short8*)(Bsl + (wn + 16 + fr) * 40 + fc);
    acc00 = __builtin_amdgcn_mfma_f32_16x16x32_bf16(a0h, b0h, acc00, 0, 0, 0);
    acc01 = __builtin_amdgcn_mfma_f32_16x16x32_bf16(a0h, b1h, acc01, 0, 0, 0);
    acc10 = __builtin_amdgcn_mfma_f32_16x16x32_bf16(a1h, b0h, acc10, 0, 0, 0);
    acc11 = __builtin_amdgcn_mfma_f32_16x16x32_bf16(a1h, b1h, acc11, 0, 0, 0);
    acc00 = __builtin_amdgcn_mfma_f32_16x16x32_bf16(a0h, b0l, acc00, 0, 0, 0);
    acc01 = __builtin_amdgcn_mfma_f32_16x16x32_bf16(a0h, b1l, acc01, 0, 0, 0);
    acc10 = __builtin_amdgcn_mfma_f32_16x16x32_bf16(a1h, b0l, acc10, 0, 0, 0);
    acc11 = __builtin_amdgcn_mfma_f32_16x16x32_bf16(a1h, b1l, acc11, 0, 0, 0);
    acc00 = __builtin_amdgcn_mfma_f32_16x16x32_bf16(a0l, b0h, acc00, 0, 0, 0);
    acc01 = __builtin_amdgcn_mfma_f32_16x16x32_bf16(a0l, b1h, acc01, 0, 0, 0);
    acc10 = __builtin_amdgcn_mfma_f32_16x16x32_bf16(a1l, b0h, acc10, 0, 0, 0);
    acc11 = __builtin_amdgcn_mfma_f32_16x16x32_bf16(a1l, b1h, acc11, 0, 0, 0);
  }
  int crow = (lane >> 4) << 2;
  int ccol = lane & 15;
  f32x4 accs[2][2] = {{acc00, acc01}, {acc10, acc11}};
#pragma unroll
  for (int i = 0; i < 2; ++i)
#pragma unroll
    for (int j = 0; j < 2; ++j) {
      int r0 = bm * 64 + wm + 16 * i + crow;
      int c0 = bn * 64 + wn + 16 * j + ccol;
#pragma unroll
      for (int rg = 0; rg < 4; ++rg) {
        size_t off = (size_t)(r0 + rg) * Nc + c0;
        float v = accs[i][j][rg] * alpha;
        if constexpr (BIAS) v += bias[c0];
        Cb[off] = v;
      }
    }
}

// plain NT GEMM (bf16), used for P @ X with scale-ptr accumulate
template <bool ACCUM, bool SCALEPTR>
__global__ __launch_bounds__(256) void gemm_nt(
    const u16* __restrict__ A, const u16* __restrict__ B, float* __restrict__ C,
    const float* __restrict__ scptr, float alpha, int M, int Nc, int Kd) {
  int bn = blockIdx.x, bm = blockIdx.y;
  int tid = threadIdx.x;
  int wid = tid >> 6, lane = tid & 63;
  __shared__ u16 As[64 * 40];
  __shared__ u16 Bs[64 * 40];
  f32x4 acc00 = {}, acc01 = {}, acc10 = {}, acc11 = {};
  int lr = tid >> 2;
  int lc = (tid & 3) << 3;
  const u16* Ag = A + (size_t)(bm * 64 + lr) * Kd + lc;
  const u16* Bg = B + (size_t)(bn * 64 + lr) * Kd + lc;
  int wm = (wid & 1) * 32, wn = (wid >> 1) * 32;
  int fr = lane & 15;
  int fc = (lane >> 4) << 3;
  for (int k0 = 0; k0 < Kd; k0 += 32) {
    uint4 av = *(const uint4*)(Ag + k0);
    uint4 bv = *(const uint4*)(Bg + k0);
    __syncthreads();
    *(uint4*)(As + lr * 40 + lc) = av;
    *(uint4*)(Bs + lr * 40 + lc) = bv;
    __syncthreads();
    short8 a0 = *(const short8*)(As + (wm + fr) * 40 + fc);
    short8 a1 = *(const short8*)(As + (wm + 16 + fr) * 40 + fc);
    short8 b0 = *(const short8*)(Bs + (wn + fr) * 40 + fc);
    short8 b1 = *(const short8*)(Bs + (wn + 16 + fr) * 40 + fc);
    acc00 = __builtin_amdgcn_mfma_f32_16x16x32_bf16(a0, b0, acc00, 0, 0, 0);
    acc01 = __builtin_amdgcn_mfma_f32_16x16x32_bf16(a0, b1, acc01, 0, 0, 0);
    acc10 = __builtin_amdgcn_mfma_f32_16x16x32_bf16(a1, b0, acc10, 0, 0, 0);
    acc11 = __builtin_amdgcn_mfma_f32_16x16x32_bf16(a1, b1, acc11, 0, 0, 0);
  }
  float sc = alpha;
  if constexpr (SCALEPTR) sc *= *scptr;
  int crow = (lane >> 4) << 2;
  int ccol = lane & 15;
  f32x4 accs[2][2] = {{acc00, acc01}, {acc10, acc11}};
#pragma unroll
  for (int i = 0; i < 2; ++i)
#pragma unroll
    for (int j = 0; j < 2; ++j) {
      int r0 = bm * 64 + wm + 16 * i + crow;
      int c0 = bn * 64 + wn + 16 * j + ccol;
#pragma unroll
      for (int rg = 0; rg < 4; ++rg) {
        size_t off = (size_t)(r0 + rg) * Nc + c0;
        float v = accs[i][j][rg] * sc;
        if constexpr (ACCUM)
          C[off] += v;
        else
          C[off] = v;
      }
    }
}

// bf16 transpose
__global__ __launch_bounds__(256) void transpose_bf16(
    const u16* __restrict__ in, u16* __restrict__ out, int rows, int cols) {
  __shared__ u16 t[32][33];
  const u16* ib = in + (size_t)blockIdx.z * rows * cols;
  u16* ob = out + (size_t)blockIdx.z * rows * cols;
  int r0 = blockIdx.x * 32, c0 = blockIdx.y * 32;
  int tx = threadIdx.x & 31, ty = threadIdx.x >> 5;
#pragma unroll
  for (int i = 0; i < 32; i += 8)
    t[ty + i][tx] = ib[(size_t)(r0 + ty + i) * cols + c0 + tx];
  __syncthreads();
#pragma unroll
  for (int i = 0; i < 32; i += 8)
    ob[(size_t)(c0 + ty + i) * rows + r0 + tx] = t[tx][ty + i];
}

// scalars: w=softmax(alpha)->scal[0..3], rho=sigmoid(rho_raw)->scal[4]
__global__ void prep_scalars(const void* __restrict__ alpha,
                             const void* __restrict__ rho_raw,
                             float* __restrict__ scal,
                             const int* __restrict__ flag) {
  if (threadIdx.x == 0) {
    int f = *flag;
    float a[4], e[4], m = -1e30f, s = 0.f;
    for (int i = 0; i < 4; ++i) {
      a[i] = f ? ((const float*)alpha)[i] : b2f(((const u16*)alpha)[i]);
      m = fmaxf(m, a[i]);
    }
    for (int i = 0; i < 4; ++i) { e[i] = expf(a[i] - m); s += e[i]; }
    for (int i = 0; i < 4; ++i) scal[i] = e[i] / s;
    float rr = f ? ((const float*)rho_raw)[0] : b2f(((const u16*)rho_raw)[0]);
    scal[4] = 1.f / (1.f + expf(-rr));
  }
}

// ---------------------------------------------------------------------------
// fused per-row: softmax stats + top-16 (jax tiebreak) + P write (bf16)
// one wave per row
// ---------------------------------------------------------------------------
__global__ __launch_bounds__(256) void row_softmax_topk(
    const float* __restrict__ A, float* __restrict__ topv,
    int* __restrict__ topi, u16* __restrict__ P, int khead) {
  int wid = threadIdx.x >> 6, lane = threadIdx.x & 63;
  int row = blockIdx.x * 4 + wid;
  const float* arow = A + ((size_t)row << 12);
  float tv[16];
  int ti[16];
#pragma unroll
  for (int j = 0; j < 16; ++j) { tv[j] = -INFINITY; ti[j] = 0; }
  float m = -INFINITY, s = 0.f;
  for (int t = 0; t < 64; ++t) {
    int c = lane + (t << 6);
    float v = arow[c];
    if (v > m) { s = s * expf(m - v) + 1.f; m = v; }
    else s += expf(v - m);
    if (v > tv[15]) {
      tv[15] = v; ti[15] = c;
#pragma unroll
      for (int j = 15; j >= 1; --j) {
        if (tv[j] > tv[j - 1]) {
          float tf = tv[j]; tv[j] = tv[j - 1]; tv[j - 1] = tf;
          int tq = ti[j]; ti[j] = ti[j - 1]; ti[j - 1] = tq;
        }
      }
    }
  }
#pragma unroll
  for (int off = 32; off; off >>= 1) {
    float m2 = __shfl_xor(m, off);
    float s2 = __shfl_xor(s, off);
    float M = fmaxf(m, m2);
    s = s * expf(m - M) + s2 * expf(m2 - M);
    m = M;
  }
  float invS = 1.f / s;
  float myv = 0.f; int myi = 0; float sum16 = 0.f;
  for (int r = 0; r < 16; ++r) {
    unsigned long long key =
        ((unsigned long long)fkey(tv[0]) << 32) | (unsigned)(~(unsigned)ti[0]);
    unsigned long long k2 = key;
#pragma unroll
    for (int off = 32; off; off >>= 1) {
      unsigned long long o = __shfl_xor(k2, off);
      if (o > k2) k2 = o;
    }
    float wv = unfkey((unsigned)(k2 >> 32));
    int wi = (int)(~(unsigned)(k2 & 0xffffffffu));
    if (key == k2) {
#pragma unroll
      for (int j = 0; j < 15; ++j) { tv[j] = tv[j + 1]; ti[j] = ti[j + 1]; }
      tv[15] = -INFINITY; ti[15] = 0;
    }
    sum16 += expf(wv - m);
    if (r == lane) { myv = wv; myi = wi; }
  }
  if (lane < 16) {
    float h = expf(myv - m) * invS;
    float dn = sum16 * invS + 1e-9f;
    size_t o = (((size_t)khead << 12) + row) * 16 + lane;
    topv[o] = h / dn;
    topi[o] = myi;
  }
  // pass 2: write P row (bf16), rows just read -> L2 hit
  u16* prow = P + ((size_t)row << 12);
#pragma unroll
  for (int t = 0; t < 16; ++t) {
    int c = (t << 8) + (lane << 2);
    float4 v = *(const float4*)(arow + c);
    ushort4 b;
    b.x = f2b(expf(v.x - m) * invS);
    b.y = f2b(expf(v.y - m) * invS);
    b.z = f2b(expf(v.z - m) * invS);
    b.w = f2b(expf(v.w - m) * invS);
    *(ushort4*)(prow + c) = b;
  }
}

// ---------------------------------------------------------------------------
// sparse hypergraph: S_norm = C C^T, C[i,e]=Dvis[i]*val[e,p]*DeIS[e], i=idx[e,p]
// ---------------------------------------------------------------------------
__global__ __launch_bounds__(256) void edge_prep(
    const float* __restrict__ topv, const int* __restrict__ topi,
    float* __restrict__ Dv, int* __restrict__ cnt, float* __restrict__ DeIS) {
  int e = blockIdx.x * 256 + threadIdx.x;  // grid 64
  float s = 0.f;
#pragma unroll
  for (int p = 0; p < 16; ++p) {
    float v = topv[e * 16 + p];
    int i = topi[e * 16 + p];
    s += v;
    atomicAdd(&Dv[i], v);
    atomicAdd(&cnt[i], 1);
  }
  DeIS[e] = 1.0f / sqrtf(s + 1e-9f);
}

__global__ void dv_isqrt(const float* __restrict__ Dv, float* __restrict__ Dvis) {
  int i = blockIdx.x * 256 + threadIdx.x;
  Dvis[i] = sqrtf(1.0f / (Dv[i] + 1e-9f));
}

// exclusive scan of cnt[4096] -> rowptr[4097], cur=rowptr  (single block)
__global__ __launch_bounds__(256) void scan_rowptr(const int* __restrict__ cnt,
                                                   int* __restrict__ rowptr,
                                                   int* __restrict__ cur) {
  __shared__ int part[256];
  int tid = threadIdx.x;
  int base = tid * 16;
  int loc[16];
  int s = 0;
#pragma unroll
  for (int j = 0; j < 16; ++j) { loc[j] = s; s += cnt[base + j]; }
  part[tid] = s;
  __syncthreads();
  for (int off = 1; off < 256; off <<= 1) {
    int v = (tid >= off) ? part[tid - off] : 0;
    __syncthreads();
    part[tid] += v;
    __syncthreads();
  }
  int pre = (tid == 0) ? 0 : part[tid - 1];
#pragma unroll
  for (int j = 0; j < 16; ++j) {
    int r = pre + loc[j];
    rowptr[base + j] = r;
    cur[base + j] = r;
  }
  if (tid == 255) rowptr[4096] = part[255];
}

// fill per-edge cvals and CSR-transpose (colE, cvalR)
__global__ __launch_bounds__(256) void csr_fill(
    const float* __restrict__ topv, const int* __restrict__ topi,
    const float* __restrict__ Dvis, const float* __restrict__ DeIS,
    int* __restrict__ cur, float* __restrict__ cvals, int* __restrict__ colE,
    float* __restrict__ cvalR) {
  int e = blockIdx.x * 256 + threadIdx.x;  // grid 64
  float deis = DeIS[e];
#pragma unroll
  for (int p = 0; p < 16; ++p) {
    int i = topi[e * 16 + p];
    float c = Dvis[i] * topv[e * 16 + p] * deis;
    cvals[e * 16 + p] = c;
    int slot = atomicAdd(&cur[i], 1);
    colE[slot] = e;
    cvalR[slot] = c;
  }
}

// g[e] = sum_p c[e,p] * v[idx[e,p]]
__global__ __launch_bounds__(256) void spmv_edge(
    const float* __restrict__ cvals, const int* __restrict__ topi,
    const float* __restrict__ v, float* __restrict__ g) {
  int e = blockIdx.x * 256 + threadIdx.x;  // grid 64
  float acc = 0.f;
#pragma unroll
  for (int p = 0; p < 16; ++p)
    acc += cvals[e * 16 + p] * v[topi[e * 16 + p]];
  g[e] = acc;
}

// vout[i] = vin[i] - sum_{j in row i} cvalR[j]*g[colE[j]]   (L@v)
__global__ __launch_bounds__(256) void spmv_row(
    const int* __restrict__ rowptr, const int* __restrict__ colE,
    const float* __restrict__ cvalR, const float* __restrict__ g,
    const float* __restrict__ vin, float* __restrict__ vout) {
  int wid = threadIdx.x >> 6, lane = threadIdx.x & 63;
  int row = blockIdx.x * 4 + wid;  // grid 1024
  int s = rowptr[row], e = rowptr[row + 1];
  float acc = 0.f;
  for (int j = s + lane; j < e; j += 64) acc += cvalR[j] * g[colE[j]];
#pragma unroll
  for (int off = 32; off; off >>= 1) acc += __shfl_xor(acc, off);
  if (lane == 0) vout[row] = vin[row] - acc;
}

// G[e,:] = sum_p c[e,p] * M[idx[e,p],:]   (one wave per edge, 256 f32 cols)
__global__ __launch_bounds__(256) void spmm_edge(
    const float* __restrict__ cvals, const int* __restrict__ topi,
    const float* __restrict__ M, float* __restrict__ G) {
  int wid = threadIdx.x >> 6, lane = threadIdx.x & 63;
  int e = blockIdx.x * 4 + wid;  // grid 4096
  float4 acc = {0.f, 0.f, 0.f, 0.f};
#pragma unroll
  for (int p = 0; p < 16; ++p) {
    float c = cvals[e * 16 + p];
    int i = topi[e * 16 + p];
    float4 x = *(const float4*)(M + ((size_t)i << 8) + (lane << 2));
    acc.x += c * x.x; acc.y += c * x.y; acc.z += c * x.z; acc.w += c * x.w;
  }
  *(float4*)(G + ((size_t)e << 8) + (lane << 2)) = acc;
}

// Z[i,:] = sum_{j in row i} cvalR[j] * G[colE[j],:]   (= S_norm @ M)
__global__ __launch_bounds__(256) void spmm_row(
    const int* __restrict__ rowptr, const int* __restrict__ colE,
    const float* __restrict__ cvalR, const float* __restrict__ G,
    float* __restrict__ Z) {
  int wid = threadIdx.x >> 6, lane = threadIdx.x & 63;
  int row = blockIdx.x * 4 + wid;  // grid 1024
  float4 acc = {0.f, 0.f, 0.f, 0.f};
  int s = rowptr[row], e = rowptr[row + 1];
  for (int j = s; j < e; ++j) {
    float c = cvalR[j];
    int eg = colE[j];
    float4 gg = *(const float4*)(G + ((size_t)eg << 8) + (lane << 2));
    acc.x += c * gg.x; acc.y += c * gg.y; acc.z += c * gg.z; acc.w += c * gg.w;
  }
  *(float4*)(Z + ((size_t)row << 8) + (lane << 2)) = acc;
}

// v0: bit-exact jax.random.normal(key(1), (4096,1), f32)
__global__ __launch_bounds__(256) void init_v0(float* __restrict__ v) {
  int tid = blockIdx.x * 256 + threadIdx.x;
  unsigned j = (unsigned)(tid & 2047);
  unsigned x0 = j, x1 = j + 2048u;
  const unsigned ks0 = 0u, ks1 = 1u, ks2 = 0x1BD11BDAu;
  x0 += ks0; x1 += ks1;
#define TF_R(r)                                  \
  {                                              \
    x0 += x1;                                    \
    x1 = (x1 << (r)) | (x1 >> (32 - (r)));       \
    x1 ^= x0;                                    \
  }
  TF_R(13) TF_R(15) TF_R(26) TF_R(6)  x0 += ks1; x1 += ks2 + 1u;
  TF_R(17) TF_R(29) TF_R(16) TF_R(24) x0 += ks2; x1 += ks0 + 2u;
  TF_R(13) TF_R(15) TF_R(26) TF_R(6)  x0 += ks0; x1 += ks1 + 3u;
  TF_R(17) TF_R(29) TF_R(16) TF_R(24) x0 += ks1; x1 += ks2 + 4u;
  TF_R(13) TF_R(15) TF_R(26) TF_R(6)  x0 += ks2; x1 += ks0 + 5u;
#undef TF_R
  unsigned bits = (tid < 2048) ? x0 : x1;
  float u01 = __uint_as_float((bits >> 9) | 0x3f800000u) - 1.0f;
  const float lo = -0.99999994f;
  float u = fmaxf(lo, u01 * 2.0f + lo);
  float w = -log1pf(-u * u);
  float p;
  if (w < 5.0f) {
    float t = w - 2.5f;
    p = 2.81022636e-08f;
    p = 3.43273939e-07f + p * t;
    p = -3.5233877e-06f + p * t;
    p = -4.39150654e-06f + p * t;
    p = 0.00021858087f + p * t;
    p = -0.00125372503f + p * t;
    p = -0.00417768164f + p * t;
    p = 0.246640727f + p * t;
    p = 1.50140941f + p * t;
  } else {
    float t = sqrtf(w) - 3.0f;
    p = -0.000200214257f;
    p = 0.000100950558f + p * t;
    p = 0.00134934322f + p * t;
    p = -0.00367342844f + p * t;
    p = 0.00573950773f + p * t;
    p = -0.0076224613f + p * t;
    p = 0.00943887047f + p * t;
    p = 1.00167406f + p * t;
    p = 2.83297682f + p * t;
  }
  v[tid] = 1.41421354f * (p * u);
}

// lam = clip((w5.w6)/(w5.w5), 1e-3) -> scal[5]
__global__ __launch_bounds__(256) void pi_dots(const float* __restrict__ w5,
                                               const float* __restrict__ w6,
                                               float* __restrict__ scal) {
  __shared__ float r1[256], r2[256];
  int tid = threadIdx.x;
  float a = 0.f, b = 0.f;
  for (int i = tid; i < 4096; i += 256) {
    float x = w5[i];
    a += x * x;
    b += x * w6[i];
  }
  r1[tid] = a; r2[tid] = b;
  __syncthreads();
  for (int off = 128; off; off >>= 1) {
    if (tid < off) { r1[tid] += r1[tid + off]; r2[tid] += r2[tid + off]; }
    __syncthreads();
  }
  if (tid == 0) scal[5] = fmaxf(r2[0] / r1[0], 1e-3f);
}

// T1 = (c1-1)X - c1*SnX (all f32, elementwise)
__global__ __launch_bounds__(256) void t1_simple(
    const float* __restrict__ SnX, const float* __restrict__ Xf,
    const float* __restrict__ scal, float* __restrict__ T1) {
  int i = blockIdx.x * 256 + threadIdx.x;  // grid 4096
  float c1 = 2.0f / scal[5];
  T1[i] = (c1 - 1.0f) * Xf[i] - c1 * SnX[i];
}

// T2, cheb combine, elu, mix -> Zmix split hi/lo for final projection
__global__ __launch_bounds__(256) void combine_kernel(
    const float* __restrict__ Xf, const float* __restrict__ T1,
    const float* __restrict__ SnT1, const float* __restrict__ Zk,
    const float* __restrict__ thetaf, const float* __restrict__ scal,
    u16* __restrict__ Zmh, u16* __restrict__ Zml) {
  int idx = blockIdx.x * 256 + threadIdx.x;  // grid 4096
  int d = idx & 255;
  float c1 = 2.0f / scal[5];
  float rho = scal[4];
  float x = Xf[idx];
  float t1 = T1[idx];
  float t2 = 2.0f * ((c1 - 1.0f) * t1 - c1 * SnT1[idx]) - x;
  float o = x * thetaf[d] + t1 * thetaf[256 + d] + t2 * thetaf[512 + d];
  float zs = o > 0.0f ? o : expm1f(o);
  float zm = rho * zs + (1.0f - rho) * Zk[idx];
  u16 h = f2b(zm);
  Zmh[idx] = h;
  Zml[idx] = f2b(zm - b2f(h));
}

// ---------------------------------------------------------------------------
extern "C" void kernel_launch(void* const* d_in, const int* in_sizes, int n_in,
                              void* d_out, int out_size, void* d_ws,
                              size_t ws_size, hipStream_t stream) {
  (void)in_sizes; (void)n_in; (void)out_size;
  const void* Xin = d_in[0];
  const void* Lin = d_in[1];
  const void* alpha = d_in[2];
  const void* theta = d_in[3];
  const void* rho_raw = d_in[4];
  const void* Wpin = d_in[5];
  const void* bpin = d_in[6];
  float* out = (float*)d_out;

  char* base = (char*)d_ws;
  size_t off = 0;
  auto alloc = [&](size_t bytes) -> char* {
    char* p = base + off;
    off += (bytes + 255) & ~(size_t)255;
    return p;
  };
  float* Abuf = (float*)alloc((size_t)4096 * 4096 * 4);  // A per head; later G
  u16* Pbuf = (u16*)alloc((size_t)4096 * 4096 * 2);      // Yf alias; P per head
  u16* Yhi = (u16*)alloc((size_t)4 * 4096 * 256 * 2);
  u16* Ylo = (u16*)alloc((size_t)4 * 4096 * 256 * 2);
  u16* Xhi = (u16*)alloc((size_t)4096 * 256 * 2);
  u16* Xlo = (u16*)alloc((size_t)4096 * 256 * 2);
  float* Xf = (float*)alloc((size_t)4096 * 256 * 4);
  u16* XT = (u16*)alloc((size_t)256 * 4096 * 2);
  u16* Lhi = (u16*)alloc((size_t)4 * 256 * 256 * 2);
  u16* Llo = (u16*)alloc((size_t)4 * 256 * 256 * 2);
  u16* LThi = (u16*)alloc((size_t)4 * 256 * 256 * 2);
  u16* LTlo = (u16*)alloc((size_t)4 * 256 * 256 * 2);
  u16* Whi = (u16*)alloc((size_t)256 * 256 * 2);
  u16* Wlo = (u16*)alloc((size_t)256 * 256 * 2);
  float* Zk = (float*)alloc((size_t)4096 * 256 * 4);
  float* SnX = (float*)alloc((size_t)4096 * 256 * 4);  // then SnT1
  float* T1 = (float*)alloc((size_t)4096 * 256 * 4);
  u16* Zmh = (u16*)alloc((size_t)4096 * 256 * 2);
  u16* Zml = (u16*)alloc((size_t)4096 * 256 * 2);
  float* topv = (float*)alloc((size_t)4 * 4096 * 16 * 4);
  int* topi = (int*)alloc((size_t)4 * 4096 * 16 * 4);
  float* cvals = (float*)alloc((size_t)262144 * 4);
  int* colE = (int*)alloc((size_t)262144 * 4);
  float* cvalR = (float*)alloc((size_t)262144 * 4);
  int* rowptr = (int*)alloc(4097 * 4);
  int* cur = (int*)alloc(4096 * 4);
  int* cnt = (int*)alloc(4096 * 4);
  float* Dv = (float*)alloc(4096 * 4);
  float* Dvis = (float*)alloc(4096 * 4);
  float* DeIS = (float*)alloc(16384 * 4);
  float* gE = (float*)alloc(16384 * 4);
  float* wA = (float*)alloc(4096 * 4);
  float* wB = (float*)alloc(4096 * 4);
  float* thetaf = (float*)alloc(768 * 4);
  float* biasf = (float*)alloc(256 * 4);
  float* scal = (float*)alloc(256);
  int* flag = (int*)alloc(256);
  if (off > ws_size) return;
  float* Yf = (float*)Pbuf;   // 16 MB alias; dead before P written
  float* G = (float*)Abuf;    // 16 MB alias; dead after last head's softmax

  detect_dtype<<<1, 256, 0, stream>>>((const u16*)Xin, flag);
  split_input3<<<1024, 256, 0, stream>>>(Xin, Xhi, Xlo, Xf, 4096 * 256, flag);
  split_input3<<<256, 256, 0, stream>>>(Lin, Lhi, Llo, nullptr, 4 * 256 * 256, flag);
  split_input3<<<64, 256, 0, stream>>>(Wpin, Whi, Wlo, nullptr, 256 * 256, flag);
  conv_f32<<<1, 256, 0, stream>>>(theta, thetaf, 768, flag);
  conv_f32<<<1, 256, 0, stream>>>(bpin, biasf, 256, flag);
  prep_scalars<<<1, 64, 0, stream>>>(alpha, rho_raw, scal, flag);
  transpose_bf16<<<dim3(128, 8, 1), 256, 0, stream>>>(Xhi, XT, 4096, 256);
  transpose_bf16<<<dim3(8, 8, 4), 256, 0, stream>>>(Lhi, LThi, 256, 256);
  transpose_bf16<<<dim3(8, 8, 4), 256, 0, stream>>>(Llo, LTlo, 256, 256);
  // Yf = X @ L_k (split, fused), batched z=4
  gemm3_nt<false><<<dim3(4, 64, 4), 256, 0, stream>>>(
      Xhi, Xlo, LThi, LTlo, Yf, nullptr, 1.0f, 4096, 256, 256,
      0L, 256L * 256L, 4096L * 256L);
  split_f32<<<2048, 256, 0, stream>>>(Yf, Yhi, Ylo, 4 * 4096 * 256);
  hipMemsetAsync(Zk, 0, (size_t)4096 * 256 * 4, stream);
  for (int k = 0; k < 4; ++k) {
    // A = Y_k @ X^T / 16 (split, fused — single C write)
    gemm3_nt<false><<<dim3(64, 64, 1), 256, 0, stream>>>(
        Yhi + (size_t)k * 4096 * 256, Ylo + (size_t)k * 4096 * 256, Xhi, Xlo,
        Abuf, nullptr, 0.0625f, 4096, 4096, 256, 0L, 0L, 0L);
    row_softmax_topk<<<1024, 256, 0, stream>>>(Abuf, topv, topi, Pbuf, k);
    // Zk += w_k * P @ X
    gemm_nt<true, true><<<dim3(4, 64, 1), 256, 0, stream>>>(
        Pbuf, XT, Zk, scal + k, 1.0f, 4096, 256, 4096);
  }
  // sparse hypergraph Laplacian (no dense S)
  hipMemsetAsync(Dv, 0, 4096 * 4, stream);
  hipMemsetAsync(cnt, 0, 4096 * 4, stream);
  edge_prep<<<64, 256, 0, stream>>>(topv, topi, Dv, cnt, DeIS);
  dv_isqrt<<<16, 256, 0, stream>>>(Dv, Dvis);
  scan_rowptr<<<1, 256, 0, stream>>>(cnt, rowptr, cur);
  csr_fill<<<64, 256, 0, stream>>>(topv, topi, Dvis, DeIS, cur, cvals, colE,
                                   cvalR);
  init_v0<<<16, 256, 0, stream>>>(wA);
  for (int it = 0; it < 6; ++it) {
    const float* vi = (it & 1) ? wB : wA;
    float* vo = (it & 1) ? wA : wB;
    spmv_edge<<<64, 256, 0, stream>>>(cvals, topi, vi, gE);
    spmv_row<<<1024, 256, 0, stream>>>(rowptr, colE, cvalR, gE, vi, vo);
  }
  pi_dots<<<1, 256, 0, stream>>>(wB, wA, scal);
  // SnX = S_norm @ X (sparse, f32-exact)
  spmm_edge<<<4096, 256, 0, stream>>>(cvals, topi, Xf, G);
  spmm_row<<<1024, 256, 0, stream>>>(rowptr, colE, cvalR, G, SnX);
  t1_simple<<<4096, 256, 0, stream>>>(SnX, Xf, scal, T1);
  // SnT1 = S_norm @ T1 (overwrite SnX)
  spmm_edge<<<4096, 256, 0, stream>>>(cvals, topi, T1, G);
  spmm_row<<<1024, 256, 0, stream>>>(rowptr, colE, cvalR, G, SnX);
  combine_kernel<<<4096, 256, 0, stream>>>(Xf, T1, SnX, Zk, thetaf, scal, Zmh,
                                           Zml);
  // out = Zmix @ proj_w^T + proj_b (split, f32 out)
  gemm3_nt<true><<<dim3(4, 64, 1), 256, 0, stream>>>(
      Zmh, Zml, Whi, Wlo, out, biasf, 1.0f, 4096, 256, 256, 0L, 0L, 0L);
}